// Round 1
// baseline (266.112 us; speedup 1.0000x reference)
//
#include <hip/hip_runtime.h>
#include <hip/hip_bf16.h>

// Problem constants
#define B_  8
#define L_  1024
#define D_  1024
#define N_  16
#define R_  64
#define NC_ 1000

// ---------------------------------------------------------------------------
// Kernel 1: xdb[m][k] = sum_d x[m][d] * W_xproj[k][d]   (m = b*L+l, 8192 rows)
// Tile: 32 rows x 96 cols per block, K-step 32. 256 threads (tx16 x ty16),
// each thread owns 2 rows x 6 cols.
// ---------------------------------------------------------------------------
__global__ __launch_bounds__(256) void xproj_kernel(
    const float* __restrict__ x, const float* __restrict__ W,
    float* __restrict__ xdb) {
  __shared__ float xs[32][36];
  __shared__ float wsm[96][36];
  const int tid = threadIdx.x;
  const int tx = tid & 15, ty = tid >> 4;
  const int m0 = blockIdx.x * 32;

  float acc[2][6];
#pragma unroll
  for (int r = 0; r < 2; ++r)
#pragma unroll
    for (int j = 0; j < 6; ++j) acc[r][j] = 0.f;

  for (int k0 = 0; k0 < D_; k0 += 32) {
    __syncthreads();
    {  // stage x tile: 32x32 floats, 1 float4/thread
      const int row = tid >> 3, c4 = tid & 7;
      float4 v = *(const float4*)(x + (size_t)(m0 + row) * D_ + k0 + c4 * 4);
      *(float4*)(&xs[row][c4 * 4]) = v;
    }
#pragma unroll
    for (int j = 0; j < 3; ++j) {  // stage W tile: 96x32 floats
      const int idx = tid + j * 256;
      const int wr = idx >> 3, c4 = idx & 7;
      float4 v = *(const float4*)(W + (size_t)wr * D_ + k0 + c4 * 4);
      *(float4*)(&wsm[wr][c4 * 4]) = v;
    }
    __syncthreads();
#pragma unroll
    for (int kk = 0; kk < 32; kk += 4) {
      const float4 a0 = *(const float4*)(&xs[ty * 2 + 0][kk]);
      const float4 a1 = *(const float4*)(&xs[ty * 2 + 1][kk]);
#pragma unroll
      for (int j = 0; j < 6; ++j) {
        const float4 bv = *(const float4*)(&wsm[tx * 6 + j][kk]);
        acc[0][j] = fmaf(a0.x, bv.x, acc[0][j]);
        acc[0][j] = fmaf(a0.y, bv.y, acc[0][j]);
        acc[0][j] = fmaf(a0.z, bv.z, acc[0][j]);
        acc[0][j] = fmaf(a0.w, bv.w, acc[0][j]);
        acc[1][j] = fmaf(a1.x, bv.x, acc[1][j]);
        acc[1][j] = fmaf(a1.y, bv.y, acc[1][j]);
        acc[1][j] = fmaf(a1.z, bv.z, acc[1][j]);
        acc[1][j] = fmaf(a1.w, bv.w, acc[1][j]);
      }
    }
  }
#pragma unroll
  for (int r = 0; r < 2; ++r)
#pragma unroll
    for (int j = 0; j < 6; ++j)
      xdb[(size_t)(m0 + ty * 2 + r) * 96 + tx * 6 + j] = acc[r][j];
}

// ---------------------------------------------------------------------------
// Kernel 2: dt[m][d] = softplus( sum_r xdb[m][r] * W_dt[d][r] + b_dt[d] )
// Block: 64 rows x 256 d. Thread owns one d (W_dt row in 16 float4 regs),
// loops 64 rows reading dt_r from LDS (uniform/broadcast reads).
// ---------------------------------------------------------------------------
__global__ __launch_bounds__(256) void dt_kernel(
    const float* __restrict__ xdb, const float* __restrict__ W_dt,
    const float* __restrict__ b_dt, float* __restrict__ dtb) {
  __shared__ float dtr[64][64];  // 16 KB
  const int tid = threadIdx.x;
  const int d = blockIdx.y * 256 + tid;
  const int m0 = blockIdx.x * 64;

  float4 w[16];
#pragma unroll
  for (int i = 0; i < 16; ++i)
    w[i] = *(const float4*)(W_dt + (size_t)d * R_ + i * 4);
  const float bd = b_dt[d];

  // stage 64 rows x 64 floats of dt_r
#pragma unroll
  for (int j = 0; j < 4; ++j) {
    const int f4 = tid + j * 256;       // float4 index, 1024 total
    const int row = f4 >> 4, c4 = f4 & 15;
    float4 v = *(const float4*)(xdb + (size_t)(m0 + row) * 96 + c4 * 4);
    *(float4*)(&dtr[row][c4 * 4]) = v;
  }
  __syncthreads();

#pragma unroll 4
  for (int row = 0; row < 64; ++row) {
    float a0 = 0.f, a1 = 0.f, a2 = 0.f, a3 = 0.f;
#pragma unroll
    for (int rc = 0; rc < 16; ++rc) {
      const float4 v = *(const float4*)(&dtr[row][rc * 4]);
      a0 = fmaf(v.x, w[rc].x, a0);
      a1 = fmaf(v.y, w[rc].y, a1);
      a2 = fmaf(v.z, w[rc].z, a2);
      a3 = fmaf(v.w, w[rc].w, a3);
    }
    const float s = bd + ((a0 + a1) + (a2 + a3));
    // softplus = max(s,0) + log1p(exp(-|s|))
    const float sp = fmaxf(s, 0.f) + log1pf(__expf(-fabsf(s)));
    dtb[(size_t)(m0 + row) * D_ + d] = sp;
  }
}

// ---------------------------------------------------------------------------
// Kernel 3: the scan. One thread per (b, d, n). Each thread accumulates
//   acc = sum_t h_t * C[b,t,n]   with   h_t = exp(dt*A[d,n])*h_{t-1} + dt*B[b,t,n]*x[b,t,d]
// then a 16-lane shuffle reduce over n, plus the D_param*x skip term, gives
// pooled[b,d] = mean_t y. Block: 512 threads = 32 d x 16 n. Grid: B x (D/32).
// ---------------------------------------------------------------------------
__global__ __launch_bounds__(512) void scan_kernel(
    const float* __restrict__ x, const float* __restrict__ xdb,
    const float* __restrict__ dtb, const float* __restrict__ A_log,
    const float* __restrict__ D_param, float* __restrict__ pooled) {
  const int tid = threadIdx.x;
  const int n = tid & 15;
  const int dl = tid >> 4;               // 0..31
  const int b = blockIdx.x >> 5;         // grid = B*32
  const int dc = blockIdx.x & 31;
  const int d = dc * 32 + dl;

  const float Aval = -__expf(A_log[(size_t)d * N_ + n]);

  const float* xp = x + ((size_t)b * L_) * D_ + d;        // stride D_ per t
  const float* dtp = dtb + ((size_t)b * L_) * D_ + d;     // stride D_ per t
  const float* bp = xdb + ((size_t)b * L_) * 96 + 64 + n; // stride 96 per t
  const float* cp = xdb + ((size_t)b * L_) * 96 + 80 + n; // stride 96 per t

  float h = 0.f, acc = 0.f, xsum = 0.f;
#pragma unroll 4
  for (int t = 0; t < L_; ++t) {
    const float dtv = dtp[(size_t)t * D_];
    const float xv = xp[(size_t)t * D_];
    const float Bv = bp[(size_t)t * 96];
    const float Cv = cp[(size_t)t * 96];
    const float dA = __expf(dtv * Aval);
    h = fmaf(dA, h, dtv * Bv * xv);
    acc = fmaf(h, Cv, acc);
    xsum += xv;
  }
  // reduce over the 16 n-lanes (low 4 bits of lane id)
  acc += __shfl_xor(acc, 1);
  acc += __shfl_xor(acc, 2);
  acc += __shfl_xor(acc, 4);
  acc += __shfl_xor(acc, 8);
  if (n == 0) {
    const float total = acc + D_param[d] * xsum;
    pooled[(size_t)b * D_ + d] = total * (1.0f / (float)L_);
  }
}

// ---------------------------------------------------------------------------
// Kernel 4: logits[b][c] = dot(pooled[b,:], W_cls[c,:]) + b_cls[c]
// One wave per output; lanes split K with float4 loads; shuffle reduce.
// ---------------------------------------------------------------------------
__global__ __launch_bounds__(256) void cls_kernel(
    const float* __restrict__ pooled, const float* __restrict__ W_cls,
    const float* __restrict__ b_cls, float* __restrict__ out) {
  const int wave = threadIdx.x >> 6;
  const int lane = threadIdx.x & 63;
  const int idx = blockIdx.x * 4 + wave;  // 0..7999
  const int b = idx / NC_;
  const int c = idx % NC_;

  const float4* p4 = (const float4*)(pooled + (size_t)b * D_);
  const float4* w4 = (const float4*)(W_cls + (size_t)c * D_);
  float s0 = 0.f, s1 = 0.f, s2 = 0.f, s3 = 0.f;
#pragma unroll
  for (int i = 0; i < 4; ++i) {
    const float4 p = p4[i * 64 + lane];
    const float4 w = w4[i * 64 + lane];
    s0 = fmaf(p.x, w.x, s0);
    s1 = fmaf(p.y, w.y, s1);
    s2 = fmaf(p.z, w.z, s2);
    s3 = fmaf(p.w, w.w, s3);
  }
  float s = (s0 + s1) + (s2 + s3);
#pragma unroll
  for (int off = 32; off >= 1; off >>= 1) s += __shfl_xor(s, off);
  if (lane == 0) out[idx] = s + b_cls[c];
}

// ---------------------------------------------------------------------------
extern "C" void kernel_launch(void* const* d_in, const int* in_sizes, int n_in,
                              void* d_out, int out_size, void* d_ws,
                              size_t ws_size, hipStream_t stream) {
  const float* x = (const float*)d_in[0];
  const float* A_log = (const float*)d_in[1];
  const float* D_param = (const float*)d_in[2];
  const float* W_xproj = (const float*)d_in[3];
  const float* W_dt = (const float*)d_in[4];
  const float* b_dt = (const float*)d_in[5];
  const float* W_cls = (const float*)d_in[6];
  const float* b_cls = (const float*)d_in[7];
  float* out = (float*)d_out;

  float* ws = (float*)d_ws;
  float* xdb = ws;                          // 8192*96      = 786432 floats
  float* dtb = xdb + (size_t)8192 * 96;     // 8192*1024    = 8388608 floats
  float* pooled = dtb + (size_t)8192 * 1024;  // 8192 floats

  xproj_kernel<<<dim3(8192 / 32), dim3(256), 0, stream>>>(x, W_xproj, xdb);
  dt_kernel<<<dim3(8192 / 64, 4), dim3(256), 0, stream>>>(xdb, W_dt, b_dt, dtb);
  scan_kernel<<<dim3(B_ * 32), dim3(512), 0, stream>>>(x, xdb, dtb, A_log,
                                                       D_param, pooled);
  cls_kernel<<<dim3(2000), dim3(256), 0, stream>>>(pooled, W_cls, b_cls, out);
}

// Round 2
// 210.704 us; speedup vs baseline: 1.2630x; 1.2630x over previous
//
#include <hip/hip_runtime.h>
#include <hip/hip_bf16.h>

// Problem constants
#define B_  8
#define L_  1024
#define D_  1024
#define N_  16
#define R_  64
#define NC_ 1000
#define CH_ 4            // scan chunks per (b,d,n)
#define TCH (L_ / CH_)   // 256 timesteps per chunk

// ---------------------------------------------------------------------------
// Kernel 1: xdb[m][k] = sum_d x[m][d] * W_xproj[k][d]   (m = b*L+l, 8192 rows)
// Tile: 32 rows x 96 cols per block, K-step 32. 256 threads (tx16 x ty16),
// each thread owns 2 rows x 6 cols.
// ---------------------------------------------------------------------------
__global__ __launch_bounds__(256) void xproj_kernel(
    const float* __restrict__ x, const float* __restrict__ W,
    float* __restrict__ xdb) {
  __shared__ float xs[32][36];
  __shared__ float wsm[96][36];
  const int tid = threadIdx.x;
  const int tx = tid & 15, ty = tid >> 4;
  const int m0 = blockIdx.x * 32;

  float acc[2][6];
#pragma unroll
  for (int r = 0; r < 2; ++r)
#pragma unroll
    for (int j = 0; j < 6; ++j) acc[r][j] = 0.f;

  for (int k0 = 0; k0 < D_; k0 += 32) {
    __syncthreads();
    {  // stage x tile: 32x32 floats, 1 float4/thread
      const int row = tid >> 3, c4 = tid & 7;
      float4 v = *(const float4*)(x + (size_t)(m0 + row) * D_ + k0 + c4 * 4);
      *(float4*)(&xs[row][c4 * 4]) = v;
    }
#pragma unroll
    for (int j = 0; j < 3; ++j) {  // stage W tile: 96x32 floats
      const int idx = tid + j * 256;
      const int wr = idx >> 3, c4 = idx & 7;
      float4 v = *(const float4*)(W + (size_t)wr * D_ + k0 + c4 * 4);
      *(float4*)(&wsm[wr][c4 * 4]) = v;
    }
    __syncthreads();
#pragma unroll
    for (int kk = 0; kk < 32; kk += 4) {
      const float4 a0 = *(const float4*)(&xs[ty * 2 + 0][kk]);
      const float4 a1 = *(const float4*)(&xs[ty * 2 + 1][kk]);
#pragma unroll
      for (int j = 0; j < 6; ++j) {
        const float4 bv = *(const float4*)(&wsm[tx * 6 + j][kk]);
        acc[0][j] = fmaf(a0.x, bv.x, acc[0][j]);
        acc[0][j] = fmaf(a0.y, bv.y, acc[0][j]);
        acc[0][j] = fmaf(a0.z, bv.z, acc[0][j]);
        acc[0][j] = fmaf(a0.w, bv.w, acc[0][j]);
        acc[1][j] = fmaf(a1.x, bv.x, acc[1][j]);
        acc[1][j] = fmaf(a1.y, bv.y, acc[1][j]);
        acc[1][j] = fmaf(a1.z, bv.z, acc[1][j]);
        acc[1][j] = fmaf(a1.w, bv.w, acc[1][j]);
      }
    }
  }
#pragma unroll
  for (int r = 0; r < 2; ++r)
#pragma unroll
    for (int j = 0; j < 6; ++j)
      xdb[(size_t)(m0 + ty * 2 + r) * 96 + tx * 6 + j] = acc[r][j];
}

// ---------------------------------------------------------------------------
// Kernel 2: dt[m][d] = softplus( sum_r xdb[m][r] * W_dt[d][r] + b_dt[d] )
// Block: 32 rows x 256 d (m-tile shrunk 64->32 for 4 blocks/CU latency
// hiding). Thread owns one d (W_dt row in 16 float4 regs), loops 32 rows
// reading dt_r from LDS (uniform/broadcast reads).
// ---------------------------------------------------------------------------
__global__ __launch_bounds__(256) void dt_kernel(
    const float* __restrict__ xdb, const float* __restrict__ W_dt,
    const float* __restrict__ b_dt, float* __restrict__ dtb) {
  __shared__ float dtr[32][64];  // 8 KB
  const int tid = threadIdx.x;
  const int d = blockIdx.y * 256 + tid;
  const int m0 = blockIdx.x * 32;

  float4 w[16];
#pragma unroll
  for (int i = 0; i < 16; ++i)
    w[i] = *(const float4*)(W_dt + (size_t)d * R_ + i * 4);
  const float bd = b_dt[d];

  // stage 32 rows x 64 floats of dt_r (512 float4, 2 per thread)
#pragma unroll
  for (int j = 0; j < 2; ++j) {
    const int f4 = tid + j * 256;
    const int row = f4 >> 4, c4 = f4 & 15;
    float4 v = *(const float4*)(xdb + (size_t)(m0 + row) * 96 + c4 * 4);
    *(float4*)(&dtr[row][c4 * 4]) = v;
  }
  __syncthreads();

#pragma unroll 4
  for (int row = 0; row < 32; ++row) {
    float a0 = 0.f, a1 = 0.f, a2 = 0.f, a3 = 0.f;
#pragma unroll
    for (int rc = 0; rc < 16; ++rc) {
      const float4 v = *(const float4*)(&dtr[row][rc * 4]);
      a0 = fmaf(v.x, w[rc].x, a0);
      a1 = fmaf(v.y, w[rc].y, a1);
      a2 = fmaf(v.z, w[rc].z, a2);
      a3 = fmaf(v.w, w[rc].w, a3);
    }
    const float s = bd + ((a0 + a1) + (a2 + a3));
    const float sp = fmaxf(s, 0.f) + log1pf(__expf(-fabsf(s)));
    dtb[(size_t)(m0 + row) * D_ + d] = sp;
  }
}

// ---------------------------------------------------------------------------
// Kernel 3: chunked scan. The recurrence h_t = dA_t h_{t-1} + dBx_t is
// linear, so chunk c over t in [c*TCH,(c+1)*TCH) computes:
//   cumP_t = prod_{s<=t} dA_s ; loc_t = local scan with h_in = 0
//   P = cumP_end, S1 = sum cumP_t C_t, S2 = sum loc_t C_t, hend = loc_end
// Then h_t = cumP_t*h_in + loc_t  =>  acc_chunk = h_in*S1 + S2, and
// h_in(c+1) = P*h_in + hend. A 4-step LDS combine reconstructs the exact
// serial result. Block: 512 = 8 d x 16 n x 4 chunks; grid B*128 -> 4
// blocks/CU = 32 waves/CU (was 2 waves/SIMD -> latency-bound).
// ---------------------------------------------------------------------------
__global__ __launch_bounds__(512) void scan_kernel(
    const float* __restrict__ x, const float* __restrict__ xdb,
    const float* __restrict__ dtb, const float* __restrict__ A_log,
    const float* __restrict__ D_param, float* __restrict__ pooled) {
  __shared__ float lds[CH_][8][16][5];
  const int tid = threadIdx.x;
  const int n = tid & 15;
  const int dl = (tid >> 4) & 7;
  const int c = tid >> 7;                // 0..3
  const int b = blockIdx.x >> 7;         // grid = B*128
  const int dc = blockIdx.x & 127;
  const int d = dc * 8 + dl;

  const float Aval = -__expf(A_log[(size_t)d * N_ + n]);

  const size_t t0 = (size_t)c * TCH;
  const float* xp  = x   + ((size_t)b * L_ + t0) * D_ + d;
  const float* dtp = dtb + ((size_t)b * L_ + t0) * D_ + d;
  const float* bp  = xdb + ((size_t)b * L_ + t0) * 96 + 64 + n;
  const float* cp  = xdb + ((size_t)b * L_ + t0) * 96 + 80 + n;

  float cumP = 1.f, loc = 0.f, S1 = 0.f, S2 = 0.f, xsum = 0.f;
#pragma unroll 4
  for (int t = 0; t < TCH; ++t) {
    const float dtv = dtp[(size_t)t * D_];
    const float xv  = xp[(size_t)t * D_];
    const float Bv  = bp[(size_t)t * 96];
    const float Cv  = cp[(size_t)t * 96];
    const float dA  = __expf(dtv * Aval);
    cumP *= dA;
    loc  = fmaf(dA, loc, dtv * Bv * xv);
    S1   = fmaf(cumP, Cv, S1);
    S2   = fmaf(loc,  Cv, S2);
    xsum += xv;
  }
  lds[c][dl][n][0] = cumP;
  lds[c][dl][n][1] = S1;
  lds[c][dl][n][2] = S2;
  lds[c][dl][n][3] = loc;   // hend
  lds[c][dl][n][4] = xsum;
  __syncthreads();
  if (c == 0) {
    float hin = 0.f, acc = 0.f, xs = 0.f;
#pragma unroll
    for (int cc = 0; cc < CH_; ++cc) {
      acc = fmaf(hin, lds[cc][dl][n][1], acc) + lds[cc][dl][n][2];
      hin = fmaf(lds[cc][dl][n][0], hin, lds[cc][dl][n][3]);
      xs += lds[cc][dl][n][4];
    }
    // reduce over the 16 n-lanes (low 4 bits of lane id)
    acc += __shfl_xor(acc, 1);
    acc += __shfl_xor(acc, 2);
    acc += __shfl_xor(acc, 4);
    acc += __shfl_xor(acc, 8);
    if (n == 0) {
      pooled[(size_t)b * D_ + d] =
          (acc + D_param[d] * xs) * (1.0f / (float)L_);
    }
  }
}

// ---------------------------------------------------------------------------
// Kernel 4: logits[b][c] = dot(pooled[b,:], W_cls[c,:]) + b_cls[c]
// One wave per output; lanes split K with float4 loads; shuffle reduce.
// ---------------------------------------------------------------------------
__global__ __launch_bounds__(256) void cls_kernel(
    const float* __restrict__ pooled, const float* __restrict__ W_cls,
    const float* __restrict__ b_cls, float* __restrict__ out) {
  const int wave = threadIdx.x >> 6;
  const int lane = threadIdx.x & 63;
  const int idx = blockIdx.x * 4 + wave;  // 0..7999
  const int b = idx / NC_;
  const int c = idx % NC_;

  const float4* p4 = (const float4*)(pooled + (size_t)b * D_);
  const float4* w4 = (const float4*)(W_cls + (size_t)c * D_);
  float s0 = 0.f, s1 = 0.f, s2 = 0.f, s3 = 0.f;
#pragma unroll
  for (int i = 0; i < 4; ++i) {
    const float4 p = p4[i * 64 + lane];
    const float4 w = w4[i * 64 + lane];
    s0 = fmaf(p.x, w.x, s0);
    s1 = fmaf(p.y, w.y, s1);
    s2 = fmaf(p.z, w.z, s2);
    s3 = fmaf(p.w, w.w, s3);
  }
  float s = (s0 + s1) + (s2 + s3);
#pragma unroll
  for (int off = 32; off >= 1; off >>= 1) s += __shfl_xor(s, off);
  if (lane == 0) out[idx] = s + b_cls[c];
}

// ---------------------------------------------------------------------------
extern "C" void kernel_launch(void* const* d_in, const int* in_sizes, int n_in,
                              void* d_out, int out_size, void* d_ws,
                              size_t ws_size, hipStream_t stream) {
  const float* x = (const float*)d_in[0];
  const float* A_log = (const float*)d_in[1];
  const float* D_param = (const float*)d_in[2];
  const float* W_xproj = (const float*)d_in[3];
  const float* W_dt = (const float*)d_in[4];
  const float* b_dt = (const float*)d_in[5];
  const float* W_cls = (const float*)d_in[6];
  const float* b_cls = (const float*)d_in[7];
  float* out = (float*)d_out;

  float* ws = (float*)d_ws;
  float* xdb = ws;                            // 8192*96   floats
  float* dtb = xdb + (size_t)8192 * 96;       // 8192*1024 floats
  float* pooled = dtb + (size_t)8192 * 1024;  // 8192 floats

  xproj_kernel<<<dim3(8192 / 32), dim3(256), 0, stream>>>(x, W_xproj, xdb);
  dt_kernel<<<dim3(8192 / 32, 4), dim3(256), 0, stream>>>(xdb, W_dt, b_dt, dtb);
  scan_kernel<<<dim3(B_ * 128), dim3(512), 0, stream>>>(x, xdb, dtb, A_log,
                                                        D_param, pooled);
  cls_kernel<<<dim3(2000), dim3(256), 0, stream>>>(pooled, W_cls, b_cls, out);
}

// Round 3
// 172.852 us; speedup vs baseline: 1.5395x; 1.2190x over previous
//
#include <hip/hip_runtime.h>
#include <hip/hip_bf16.h>

// Problem constants
#define B_  8
#define L_  1024
#define D_  1024
#define N_  16
#define R_  64
#define NC_ 1000
#define CH_ 4            // scan chunks per (b,d,n)
#define TCH (L_ / CH_)   // 256 timesteps per chunk

#define XP_KS   8        // xproj split-K factor
#define XP_TM   64       // xproj rows per block
#define XP_KC   (D_ / XP_KS)  // 128 K per block
#define XP_M    (B_ * L_)     // 8192

// ---------------------------------------------------------------------------
// Kernel 1a: partial xproj. part[ks][m][96] = sum_{k in slice ks} x[m][k]*W[c][k]
// Grid (M/TM, KS) = (128, 8) = 1024 blocks (4/CU). 256 threads:
// tx = tid&7 -> 12 cols, ty = tid>>3 -> 2 rows. K-step 32, 4 steps/block.
// W staged TRANSPOSED (wt[kk][col], pad 100) so compute reads are 3x
// ds_read_b128 across cols 12*tx: banks (12tx)%32 hit 8 distinct 4-bank
// groups covering all 32 banks; ty-duplicates broadcast. Conflict-free.
// x staged [64][36]: row-broadcast reads, (4r+kk)%32 -> 2-way max (free).
// ---------------------------------------------------------------------------
__global__ __launch_bounds__(256) void xproj_kernel(
    const float* __restrict__ x, const float* __restrict__ W,
    float* __restrict__ part) {
  __shared__ float xs[XP_TM][36];   // 9 KB
  __shared__ float wt[32][100];     // 12.5 KB
  const int tid = threadIdx.x;
  const int tx = tid & 7;           // 12 cols each
  const int ty = tid >> 3;          // 2 rows each
  const int m0 = blockIdx.x * XP_TM;
  const int ks = blockIdx.y;

  float acc[2][12];
#pragma unroll
  for (int r = 0; r < 2; ++r)
#pragma unroll
    for (int j = 0; j < 12; ++j) acc[r][j] = 0.f;

  for (int step = 0; step < XP_KC / 32; ++step) {
    const int kbase = ks * XP_KC + step * 32;
    __syncthreads();
    // stage x tile: 64 rows x 32 cols = 512 float4, 2 per thread
#pragma unroll
    for (int j = 0; j < 2; ++j) {
      const int f4 = tid + j * 256;
      const int row = f4 >> 3, c4 = f4 & 7;
      float4 v = *(const float4*)(x + (size_t)(m0 + row) * D_ + kbase + c4 * 4);
      *(float4*)(&xs[row][c4 * 4]) = v;
    }
    // stage W tile transposed: 96 rows x 32 k = 768 float4, 3 per thread
#pragma unroll
    for (int j = 0; j < 3; ++j) {
      const int idx = tid + j * 256;
      const int wr = idx >> 3, c4 = idx & 7;
      float4 v = *(const float4*)(W + (size_t)wr * D_ + kbase + c4 * 4);
      wt[c4 * 4 + 0][wr] = v.x;
      wt[c4 * 4 + 1][wr] = v.y;
      wt[c4 * 4 + 2][wr] = v.z;
      wt[c4 * 4 + 3][wr] = v.w;
    }
    __syncthreads();
#pragma unroll 4
    for (int kk = 0; kk < 32; ++kk) {
      const float a0 = xs[ty * 2 + 0][kk];
      const float a1 = xs[ty * 2 + 1][kk];
      const float4 b0 = *(const float4*)(&wt[kk][tx * 12 + 0]);
      const float4 b1 = *(const float4*)(&wt[kk][tx * 12 + 4]);
      const float4 b2 = *(const float4*)(&wt[kk][tx * 12 + 8]);
      acc[0][0] = fmaf(a0, b0.x, acc[0][0]);
      acc[0][1] = fmaf(a0, b0.y, acc[0][1]);
      acc[0][2] = fmaf(a0, b0.z, acc[0][2]);
      acc[0][3] = fmaf(a0, b0.w, acc[0][3]);
      acc[0][4] = fmaf(a0, b1.x, acc[0][4]);
      acc[0][5] = fmaf(a0, b1.y, acc[0][5]);
      acc[0][6] = fmaf(a0, b1.z, acc[0][6]);
      acc[0][7] = fmaf(a0, b1.w, acc[0][7]);
      acc[0][8] = fmaf(a0, b2.x, acc[0][8]);
      acc[0][9] = fmaf(a0, b2.y, acc[0][9]);
      acc[0][10] = fmaf(a0, b2.z, acc[0][10]);
      acc[0][11] = fmaf(a0, b2.w, acc[0][11]);
      acc[1][0] = fmaf(a1, b0.x, acc[1][0]);
      acc[1][1] = fmaf(a1, b0.y, acc[1][1]);
      acc[1][2] = fmaf(a1, b0.z, acc[1][2]);
      acc[1][3] = fmaf(a1, b0.w, acc[1][3]);
      acc[1][4] = fmaf(a1, b1.x, acc[1][4]);
      acc[1][5] = fmaf(a1, b1.y, acc[1][5]);
      acc[1][6] = fmaf(a1, b1.z, acc[1][6]);
      acc[1][7] = fmaf(a1, b1.w, acc[1][7]);
      acc[1][8] = fmaf(a1, b2.x, acc[1][8]);
      acc[1][9] = fmaf(a1, b2.y, acc[1][9]);
      acc[1][10] = fmaf(a1, b2.z, acc[1][10]);
      acc[1][11] = fmaf(a1, b2.w, acc[1][11]);
    }
  }
  // write partials: part[ks][m][96]
#pragma unroll
  for (int r = 0; r < 2; ++r) {
    float* p = part + ((size_t)ks * XP_M + m0 + ty * 2 + r) * 96 + tx * 12;
    *(float4*)(p + 0) = make_float4(acc[r][0], acc[r][1], acc[r][2], acc[r][3]);
    *(float4*)(p + 4) = make_float4(acc[r][4], acc[r][5], acc[r][6], acc[r][7]);
    *(float4*)(p + 8) = make_float4(acc[r][8], acc[r][9], acc[r][10], acc[r][11]);
  }
}

// ---------------------------------------------------------------------------
// Kernel 1b: reduce the 8 K-slice partials -> xdb[m][96].
// 196608 float4 outputs; one per thread.
// ---------------------------------------------------------------------------
__global__ __launch_bounds__(256) void xreduce_kernel(
    const float* __restrict__ part, float* __restrict__ xdb) {
  const size_t gidx = (size_t)blockIdx.x * 256 + threadIdx.x;  // float4 idx
  const float4* p4 = (const float4*)part;
  const size_t stride = (size_t)XP_M * 96 / 4;  // 196608
  float4 s = p4[gidx];
#pragma unroll
  for (int ks = 1; ks < XP_KS; ++ks) {
    const float4 v = p4[(size_t)ks * stride + gidx];
    s.x += v.x; s.y += v.y; s.z += v.z; s.w += v.w;
  }
  ((float4*)xdb)[gidx] = s;
}

// ---------------------------------------------------------------------------
// Kernel 2: dt[m][d] = softplus( sum_r xdb[m][r] * W_dt[d][r] + b_dt[d] )
// Block: 32 rows x 256 d. Thread owns one d (W_dt row in 16 float4 regs),
// loops 32 rows reading dt_r from LDS (same-address broadcast reads).
// ---------------------------------------------------------------------------
__global__ __launch_bounds__(256) void dt_kernel(
    const float* __restrict__ xdb, const float* __restrict__ W_dt,
    const float* __restrict__ b_dt, float* __restrict__ dtb) {
  __shared__ float dtr[32][64];  // 8 KB
  const int tid = threadIdx.x;
  const int d = blockIdx.y * 256 + tid;
  const int m0 = blockIdx.x * 32;

  float4 w[16];
#pragma unroll
  for (int i = 0; i < 16; ++i)
    w[i] = *(const float4*)(W_dt + (size_t)d * R_ + i * 4);
  const float bd = b_dt[d];

#pragma unroll
  for (int j = 0; j < 2; ++j) {
    const int f4 = tid + j * 256;
    const int row = f4 >> 4, c4 = f4 & 15;
    float4 v = *(const float4*)(xdb + (size_t)(m0 + row) * 96 + c4 * 4);
    *(float4*)(&dtr[row][c4 * 4]) = v;
  }
  __syncthreads();

#pragma unroll 4
  for (int row = 0; row < 32; ++row) {
    float a0 = 0.f, a1 = 0.f, a2 = 0.f, a3 = 0.f;
#pragma unroll
    for (int rc = 0; rc < 16; ++rc) {
      const float4 v = *(const float4*)(&dtr[row][rc * 4]);
      a0 = fmaf(v.x, w[rc].x, a0);
      a1 = fmaf(v.y, w[rc].y, a1);
      a2 = fmaf(v.z, w[rc].z, a2);
      a3 = fmaf(v.w, w[rc].w, a3);
    }
    const float s = bd + ((a0 + a1) + (a2 + a3));
    const float sp = fmaxf(s, 0.f) + log1pf(__expf(-fabsf(s)));
    dtb[(size_t)(m0 + row) * D_ + d] = sp;
  }
}

// ---------------------------------------------------------------------------
// Kernel 3: chunked scan (linear recurrence chunk decomposition; exact).
// Block: 512 = 8 d x 16 n x 4 chunks; grid B*128 -> 32 waves/CU.
// ---------------------------------------------------------------------------
__global__ __launch_bounds__(512) void scan_kernel(
    const float* __restrict__ x, const float* __restrict__ xdb,
    const float* __restrict__ dtb, const float* __restrict__ A_log,
    const float* __restrict__ D_param, float* __restrict__ pooled) {
  __shared__ float lds[CH_][8][16][5];
  const int tid = threadIdx.x;
  const int n = tid & 15;
  const int dl = (tid >> 4) & 7;
  const int c = tid >> 7;                // 0..3
  const int b = blockIdx.x >> 7;         // grid = B*128
  const int dc = blockIdx.x & 127;
  const int d = dc * 8 + dl;

  const float Aval = -__expf(A_log[(size_t)d * N_ + n]);

  const size_t t0 = (size_t)c * TCH;
  const float* xp  = x   + ((size_t)b * L_ + t0) * D_ + d;
  const float* dtp = dtb + ((size_t)b * L_ + t0) * D_ + d;
  const float* bp  = xdb + ((size_t)b * L_ + t0) * 96 + 64 + n;
  const float* cp  = xdb + ((size_t)b * L_ + t0) * 96 + 80 + n;

  float cumP = 1.f, loc = 0.f, S1 = 0.f, S2 = 0.f, xsum = 0.f;
#pragma unroll 4
  for (int t = 0; t < TCH; ++t) {
    const float dtv = dtp[(size_t)t * D_];
    const float xv  = xp[(size_t)t * D_];
    const float Bv  = bp[(size_t)t * 96];
    const float Cv  = cp[(size_t)t * 96];
    const float dA  = __expf(dtv * Aval);
    cumP *= dA;
    loc  = fmaf(dA, loc, dtv * Bv * xv);
    S1   = fmaf(cumP, Cv, S1);
    S2   = fmaf(loc,  Cv, S2);
    xsum += xv;
  }
  lds[c][dl][n][0] = cumP;
  lds[c][dl][n][1] = S1;
  lds[c][dl][n][2] = S2;
  lds[c][dl][n][3] = loc;   // hend
  lds[c][dl][n][4] = xsum;
  __syncthreads();
  if (c == 0) {
    float hin = 0.f, acc = 0.f, xs2 = 0.f;
#pragma unroll
    for (int cc = 0; cc < CH_; ++cc) {
      acc = fmaf(hin, lds[cc][dl][n][1], acc) + lds[cc][dl][n][2];
      hin = fmaf(lds[cc][dl][n][0], hin, lds[cc][dl][n][3]);
      xs2 += lds[cc][dl][n][4];
    }
    acc += __shfl_xor(acc, 1);
    acc += __shfl_xor(acc, 2);
    acc += __shfl_xor(acc, 4);
    acc += __shfl_xor(acc, 8);
    if (n == 0) {
      pooled[(size_t)b * D_ + d] =
          (acc + D_param[d] * xs2) * (1.0f / (float)L_);
    }
  }
}

// ---------------------------------------------------------------------------
// Kernel 4: logits[b][c] = dot(pooled[b,:], W_cls[c,:]) + b_cls[c]
// ---------------------------------------------------------------------------
__global__ __launch_bounds__(256) void cls_kernel(
    const float* __restrict__ pooled, const float* __restrict__ W_cls,
    const float* __restrict__ b_cls, float* __restrict__ out) {
  const int wave = threadIdx.x >> 6;
  const int lane = threadIdx.x & 63;
  const int idx = blockIdx.x * 4 + wave;  // 0..7999
  const int b = idx / NC_;
  const int c = idx % NC_;

  const float4* p4 = (const float4*)(pooled + (size_t)b * D_);
  const float4* w4 = (const float4*)(W_cls + (size_t)c * D_);
  float s0 = 0.f, s1 = 0.f, s2 = 0.f, s3 = 0.f;
#pragma unroll
  for (int i = 0; i < 4; ++i) {
    const float4 p = p4[i * 64 + lane];
    const float4 w = w4[i * 64 + lane];
    s0 = fmaf(p.x, w.x, s0);
    s1 = fmaf(p.y, w.y, s1);
    s2 = fmaf(p.z, w.z, s2);
    s3 = fmaf(p.w, w.w, s3);
  }
  float s = (s0 + s1) + (s2 + s3);
#pragma unroll
  for (int off = 32; off >= 1; off >>= 1) s += __shfl_xor(s, off);
  if (lane == 0) out[idx] = s + b_cls[c];
}

// ---------------------------------------------------------------------------
extern "C" void kernel_launch(void* const* d_in, const int* in_sizes, int n_in,
                              void* d_out, int out_size, void* d_ws,
                              size_t ws_size, hipStream_t stream) {
  const float* x = (const float*)d_in[0];
  const float* A_log = (const float*)d_in[1];
  const float* D_param = (const float*)d_in[2];
  const float* W_xproj = (const float*)d_in[3];
  const float* W_dt = (const float*)d_in[4];
  const float* b_dt = (const float*)d_in[5];
  const float* W_cls = (const float*)d_in[6];
  const float* b_cls = (const float*)d_in[7];
  float* out = (float*)d_out;

  float* ws = (float*)d_ws;
  float* xdb = ws;                            // 8192*96 floats
  float* dtb = xdb + (size_t)8192 * 96;       // 8192*1024 floats
  float* pooled = dtb + (size_t)8192 * 1024;  // 8192 floats
  // xproj partials (25.2 MB) reuse the dtb region: consumed by xreduce
  // BEFORE dt_kernel writes dtb.
  float* part = dtb;

  xproj_kernel<<<dim3(XP_M / XP_TM, XP_KS), dim3(256), 0, stream>>>(
      x, W_xproj, part);
  xreduce_kernel<<<dim3(XP_M * 96 / 4 / 256), dim3(256), 0, stream>>>(part,
                                                                      xdb);
  dt_kernel<<<dim3(8192 / 32, 4), dim3(256), 0, stream>>>(xdb, W_dt, b_dt, dtb);
  scan_kernel<<<dim3(B_ * 128), dim3(512), 0, stream>>>(x, xdb, dtb, A_log,
                                                        D_param, pooled);
  cls_kernel<<<dim3(2000), dim3(256), 0, stream>>>(pooled, W_cls, b_cls, out);
}